// Round 8
// baseline (77.150 us; speedup 1.0000x reference)
//
#include <hip/hip_runtime.h>
#include <hip/hip_bf16.h>

#define BB 2
#define NN 1024
#define MM 1024
#define DD 256
#define HH 128
#define C2LE 2.8853900817779268f       // 2*log2(e)
#define NEG2LOG2E -2.8853900817779268f // -2*log2(e)

typedef float v2f __attribute__((ext_vector_type(2)));
typedef float v4f __attribute__((ext_vector_type(4)));

// ---- Kernel 1: e = exp2(C*(x@W + bias)).  A-side -> EaT[b][h][n] (transposed)
// B-side -> Eb[b][m][h] (row-major).
__global__ __launch_bounds__(256) void proj_kernel(
    const float* __restrict__ query, const float* __restrict__ key,
    const float* __restrict__ Wa_w, const float* __restrict__ Wa_b,
    const float* __restrict__ Wb_w, const float* __restrict__ Wb_b,
    float* __restrict__ EaT, float* __restrict__ Eb) {
    __shared__ float rows[8][DD];     // 8KB
    __shared__ float partial[8][HH];  // 4KB
    const int tid = threadIdx.x;
    const int rb = blockIdx.x * 8;
    const bool isA = rb < BB * NN;
    const float* in = isA ? query : key;
    const float* W  = isA ? Wa_w : Wb_w;
    const float* bias = isA ? Wa_b : Wb_b;
    const int base = isA ? rb : rb - BB * NN;

    const float4* in4 = (const float4*)(in + (size_t)base * DD);
    float4* rows4 = (float4*)rows;
    rows4[tid] = in4[tid];
    rows4[tid + 256] = in4[tid + 256];
    __syncthreads();

    const int h = tid & 127, half = tid >> 7;
    const int d0 = half * 128;
    float acc[8] = {};
    for (int d = d0; d < d0 + 128; d += 4) {
        const float w0 = W[(d + 0) * HH + h];
        const float w1 = W[(d + 1) * HH + h];
        const float w2 = W[(d + 2) * HH + h];
        const float w3 = W[(d + 3) * HH + h];
#pragma unroll
        for (int r = 0; r < 8; ++r) {
            const float4 rv = *(const float4*)&rows[r][d];
            acc[r] = fmaf(rv.x, w0, fmaf(rv.y, w1, fmaf(rv.z, w2, fmaf(rv.w, w3, acc[r]))));
        }
    }
    if (half) {
#pragma unroll
        for (int r = 0; r < 8; ++r) partial[r][h] = acc[r];
    }
    __syncthreads();
    if (!half) {
        const float bv = bias[h];
        float ev[8];
#pragma unroll
        for (int r = 0; r < 8; ++r)
            ev[r] = __builtin_amdgcn_exp2f(C2LE * (acc[r] + partial[r][h] + bv));
        if (isA) {
            const int bq = base >> 10, nb = base & (NN - 1);
            float* dst = EaT + ((size_t)(bq * HH + h)) * NN + nb;
            *(float4*)dst = *(float4*)&ev[0];
            *(float4*)(dst + 4) = *(float4*)&ev[4];
        } else {
#pragma unroll
            for (int r = 0; r < 8; ++r)
                Eb[(size_t)(base + r) * HH + h] = ev[r];
        }
    }
}

// ---- Kernel 2: P[b,n,m] = exp(-2 * sum_h v_h / (Ea*Eb + 1))  (unnormalized)
// Tile 32n x 256m, h-chunked (64). Lane owns 4 m; wave owns 8 n.
// 4 h-terms share one rcp; math packed over n-pairs (v2f).
__global__ __launch_bounds__(256, 1) void scores_kernel(
    const float* __restrict__ EaT, const float* __restrict__ Eb,
    const float* __restrict__ v_w, float* __restrict__ P) {
    __shared__ float b_s[256 * 64];  // 64KB, swizzled: slot = h4 ^ ((r>>2)&15)
    __shared__ float a_p[64 * 32];   // 8KB, [h][n]
    const int tid = threadIdx.x;
    const int m0 = blockIdx.x * 256, n0 = blockIdx.y * 32, b = blockIdx.z;
    const int lane = tid & 63;
    const int ng = __builtin_amdgcn_readfirstlane(threadIdx.x >> 6);

    v2f acc[4][4] = {};  // [mi][np]

    for (int hc = 0; hc < 2; ++hc) {
        __syncthreads();
        // stage b chunk: 256m x 64h
        for (int i = tid; i < 4096; i += 256) {
            const int r = i >> 4, h4 = i & 15;
            *(float4*)&b_s[r * 64 + ((h4 ^ ((r >> 2) & 15)) << 2)] =
                *(const float4*)&Eb[((size_t)(b * MM + m0 + r)) * HH + hc * 64 + h4 * 4];
        }
        // stage a chunk: 64h x 32n (from transposed EaT)
        for (int i = tid; i < 512; i += 256) {
            const int hh = i >> 3, n4 = i & 7;
            *(float4*)&a_p[hh * 32 + n4 * 4] =
                *(const float4*)&EaT[((size_t)(b * HH + hc * 64 + hh)) * NN + n0 + n4 * 4];
        }
        __syncthreads();

        const int rbase = lane * 4;
        const int skey = (lane & 15);  // (r>>2)&15 for r = lane*4+mi
#pragma unroll 4
        for (int h4 = 0; h4 < 16; ++h4) {
            float4 b4[4];
#pragma unroll
            for (int mi = 0; mi < 4; ++mi)
                b4[mi] = *(const float4*)&b_s[(rbase + mi) * 64 + ((h4 ^ skey) << 2)];
            const float4 w4 = *(const float4*)&v_w[hc * 64 + h4 * 4];  // uniform
            const float* ap = &a_p[h4 * 4 * 32 + ng * 8];
#pragma unroll
            for (int np = 0; np < 4; ++np) {
                const v2f a0 = *(const v2f*)&ap[0 * 32 + np * 2];  // broadcasts
                const v2f a1 = *(const v2f*)&ap[1 * 32 + np * 2];
                const v2f a2 = *(const v2f*)&ap[2 * 32 + np * 2];
                const v2f a3 = *(const v2f*)&ap[3 * 32 + np * 2];
#pragma unroll
                for (int mi = 0; mi < 4; ++mi) {
                    const v2f u0 = a0 * b4[mi].x + 1.0f;
                    const v2f u1 = a1 * b4[mi].y + 1.0f;
                    const v2f u2 = a2 * b4[mi].z + 1.0f;
                    const v2f u3 = a3 * b4[mi].w + 1.0f;
                    const v2f p01 = u0 * u1, p23 = u2 * u3;
                    const v2f An = w4.x * u1 + w4.y * u0;
                    const v2f Bn = w4.z * u3 + w4.w * u2;
                    const v2f num = An * p23 + Bn * p01;
                    const v2f Pp = p01 * p23;
                    v2f r2;
                    r2.x = __builtin_amdgcn_rcpf(Pp.x);
                    r2.y = __builtin_amdgcn_rcpf(Pp.y);
                    acc[mi][np] = num * r2 + acc[mi][np];
                }
            }
        }
    }

    // write: per n (8), float4 over this lane's 4 m
    const size_t rowbase = ((size_t)b * NN + n0 + ng * 8) * MM + m0 + lane * 4;
#pragma unroll
    for (int n = 0; n < 8; ++n) {
        const int np = n >> 1, c = n & 1;
        float4 o;
        o.x = __builtin_amdgcn_exp2f(acc[0][np][c] * NEG2LOG2E);
        o.y = __builtin_amdgcn_exp2f(acc[1][np][c] * NEG2LOG2E);
        o.z = __builtin_amdgcn_exp2f(acc[2][np][c] * NEG2LOG2E);
        o.w = __builtin_amdgcn_exp2f(acc[3][np][c] * NEG2LOG2E);
        *(float4*)&P[rowbase + (size_t)n * MM] = o;
    }
}

// ---- Kernel 3: PV over an m-slice (MQ=128). 8 waves x 4 rows; p staged in
// LDS, read as b128 broadcasts (4 m at a time); k float4 w/ 4-deep prefetch.
template <int NQ>
__global__ __launch_bounds__(512) void attend_kernel(
    const float* __restrict__ P, const float* __restrict__ key,
    float* __restrict__ partial, float* __restrict__ psums) {
    constexpr int MQ = MM / NQ;
    __shared__ float p[32][MQ];  // 16KB
    const int tid = threadIdx.x;
    const int wave = __builtin_amdgcn_readfirstlane(threadIdx.x >> 6);
    const int lane = tid & 63;
    const int n0 = blockIdx.x * 32;
    const int mq = blockIdx.y, b = blockIdx.z;
    const int m0 = mq * MQ;

    // stage p + row sums: wave w handles rows 4w..4w+3, 2 rows per pass
#pragma unroll
    for (int j = 0; j < 2; ++j) {
        const int rr = wave * 4 + j * 2 + (lane >> 5);
        const int c = lane & 31;
        float4 v[MQ / 128];
        float s = 0.f;
#pragma unroll
        for (int k = 0; k < MQ / 128; ++k) {
            v[k] = *(const float4*)
                &P[((size_t)b * NN + n0 + rr) * MM + m0 + k * 128 + c * 4];
            s += (v[k].x + v[k].y) + (v[k].z + v[k].w);
        }
#pragma unroll
        for (int o = 16; o > 0; o >>= 1) s += __shfl_xor(s, o);
#pragma unroll
        for (int k = 0; k < MQ / 128; ++k)
            *(float4*)&p[rr][k * 128 + c * 4] = v[k];
        if ((lane & 31) == 0) psums[((size_t)mq * BB + b) * NN + n0 + rr] = s;
    }
    __syncthreads();

    const int r0 = wave * 4;
    const float* kb = key + ((size_t)b * MM + m0) * DD + lane * 4;
    v4f acc[4] = {};
    v4f kc0 = *(const v4f*)&kb[0 * DD];
    v4f kc1 = *(const v4f*)&kb[1 * DD];
    v4f kc2 = *(const v4f*)&kb[2 * DD];
    v4f kc3 = *(const v4f*)&kb[3 * DD];

#define PV4(mm, K0, K1, K2, K3)                            \
    {                                                      \
        _Pragma("unroll")                                  \
        for (int i = 0; i < 4; ++i) {                      \
            const float4 pv = *(const float4*)&p[r0 + i][(mm)]; \
            acc[i] = K0 * pv.x + acc[i];                   \
            acc[i] = K1 * pv.y + acc[i];                   \
            acc[i] = K2 * pv.z + acc[i];                   \
            acc[i] = K3 * pv.w + acc[i];                   \
        }                                                  \
    }

    int m = 0;
    for (; m < MQ - 4; m += 4) {
        const v4f kn0 = *(const v4f*)&kb[(size_t)(m + 4) * DD];
        const v4f kn1 = *(const v4f*)&kb[(size_t)(m + 5) * DD];
        const v4f kn2 = *(const v4f*)&kb[(size_t)(m + 6) * DD];
        const v4f kn3 = *(const v4f*)&kb[(size_t)(m + 7) * DD];
        PV4(m, kc0, kc1, kc2, kc3)
        kc0 = kn0; kc1 = kn1; kc2 = kn2; kc3 = kn3;
    }
    PV4(m, kc0, kc1, kc2, kc3)
#undef PV4

    const size_t base = (((size_t)mq * BB + b) * NN + n0 + r0) * DD + lane * 4;
#pragma unroll
    for (int i = 0; i < 4; ++i)
        *(v4f*)&partial[base + (size_t)i * DD] = acc[i];
}

// ---- Kernel 4: out[b,n,d] = sum_q partial[q][b,n,d] / sum_q psums[q][b,n]
template <int NQ>
__global__ __launch_bounds__(256) void combine_kernel(
    const float* __restrict__ partial, const float* __restrict__ psums,
    float* __restrict__ out) {
    const int n = blockIdx.x, b = blockIdx.y, d = threadIdx.x;
    float s = 0.f, a = 0.f;
#pragma unroll
    for (int q = 0; q < NQ; ++q) {
        s += psums[((size_t)q * BB + b) * NN + n];
        a += partial[(((size_t)q * BB + b) * NN + n) * DD + d];
    }
    out[((size_t)b * NN + n) * DD + d] = a * __builtin_amdgcn_rcpf(s);
}

extern "C" void kernel_launch(void* const* d_in, const int* in_sizes, int n_in,
                              void* d_out, int out_size, void* d_ws, size_t ws_size,
                              hipStream_t stream) {
    const float* query = (const float*)d_in[0];
    const float* key   = (const float*)d_in[1];
    const float* Wa_w  = (const float*)d_in[2];
    const float* Wa_b  = (const float*)d_in[3];
    const float* Wb_w  = (const float*)d_in[4];
    const float* Wb_b  = (const float*)d_in[5];
    const float* v_w   = (const float*)d_in[6];
    float* out = (float*)d_out;

    float* ws = (float*)d_ws;
    float* EaT = ws;                             // B*H*N
    float* Eb  = EaT + BB * NN * HH;             // B*M*H
    float* P   = Eb + BB * MM * HH;              // B*N*M
    float* partial = P + (size_t)BB * NN * MM;   // NQ*B*N*D
    const size_t base_f =
        (size_t)(BB * NN * HH) + BB * MM * HH + (size_t)BB * NN * MM;
    const size_t need8 =
        (base_f + (size_t)8 * BB * NN * DD + (size_t)8 * BB * NN + 2048) * sizeof(float);

    proj_kernel<<<dim3((BB * NN + BB * MM) / 8), dim3(256), 0, stream>>>(
        query, key, Wa_w, Wa_b, Wb_w, Wb_b, EaT, Eb);
    scores_kernel<<<dim3(MM / 256, NN / 32, BB), dim3(256), 0, stream>>>(
        EaT, Eb, v_w, P);
    if (ws_size >= need8) {
        float* psums = partial + (size_t)8 * BB * NN * DD;
        attend_kernel<8><<<dim3(NN / 32, 8, BB), dim3(512), 0, stream>>>(
            P, key, partial, psums);
        combine_kernel<8><<<dim3(NN, BB), dim3(256), 0, stream>>>(
            partial, psums, out);
    } else {
        float* psums = partial + (size_t)4 * BB * NN * DD;
        attend_kernel<4><<<dim3(NN / 32, 4, BB), dim3(512), 0, stream>>>(
            P, key, partial, psums);
        combine_kernel<4><<<dim3(NN, BB), dim3(256), 0, stream>>>(
            partial, psums, out);
    }
}

// Round 9
// 72.884 us; speedup vs baseline: 1.0585x; 1.0585x over previous
//
#include <hip/hip_runtime.h>
#include <hip/hip_fp16.h>

#define BB 2
#define NN 1024
#define MM 1024
#define DD 256
#define HH 128
#define C2LE 2.8853900817779268f       // 2*log2(e)
#define NEG2LOG2E -2.8853900817779268f // -2*log2(e)
#define SHIFT_C -4.3280860f            // -3*log2(e): P = e^{s-3}, softmax-invariant

typedef float v2f __attribute__((ext_vector_type(2)));
typedef float v4f __attribute__((ext_vector_type(4)));
typedef _Float16 h8 __attribute__((ext_vector_type(8)));

// ---- Kernel 1: e = exp2(C*(x@W + bias)).  A-side -> EaT[b][h][n] (transposed)
// B-side -> Eb[b][m][h] (row-major).
__global__ __launch_bounds__(256) void proj_kernel(
    const float* __restrict__ query, const float* __restrict__ key,
    const float* __restrict__ Wa_w, const float* __restrict__ Wa_b,
    const float* __restrict__ Wb_w, const float* __restrict__ Wb_b,
    float* __restrict__ EaT, float* __restrict__ Eb) {
    __shared__ float rows[8][DD];     // 8KB
    __shared__ float partial[8][HH];  // 4KB
    const int tid = threadIdx.x;
    const int rb = blockIdx.x * 8;
    const bool isA = rb < BB * NN;
    const float* in = isA ? query : key;
    const float* W  = isA ? Wa_w : Wb_w;
    const float* bias = isA ? Wa_b : Wb_b;
    const int base = isA ? rb : rb - BB * NN;

    const float4* in4 = (const float4*)(in + (size_t)base * DD);
    float4* rows4 = (float4*)rows;
    rows4[tid] = in4[tid];
    rows4[tid + 256] = in4[tid + 256];
    __syncthreads();

    const int h = tid & 127, half = tid >> 7;
    const int d0 = half * 128;
    float acc[8] = {};
    for (int d = d0; d < d0 + 128; d += 4) {
        const float w0 = W[(d + 0) * HH + h];
        const float w1 = W[(d + 1) * HH + h];
        const float w2 = W[(d + 2) * HH + h];
        const float w3 = W[(d + 3) * HH + h];
#pragma unroll
        for (int r = 0; r < 8; ++r) {
            const float4 rv = *(const float4*)&rows[r][d];
            acc[r] = fmaf(rv.x, w0, fmaf(rv.y, w1, fmaf(rv.z, w2, fmaf(rv.w, w3, acc[r]))));
        }
    }
    if (half) {
#pragma unroll
        for (int r = 0; r < 8; ++r) partial[r][h] = acc[r];
    }
    __syncthreads();
    if (!half) {
        const float bv = bias[h];
        float ev[8];
#pragma unroll
        for (int r = 0; r < 8; ++r)
            ev[r] = __builtin_amdgcn_exp2f(C2LE * (acc[r] + partial[r][h] + bv));
        if (isA) {
            const int bq = base >> 10, nb = base & (NN - 1);
            float* dst = EaT + ((size_t)(bq * HH + h)) * NN + nb;
            *(float4*)dst = *(float4*)&ev[0];
            *(float4*)(dst + 4) = *(float4*)&ev[4];
        } else {
#pragma unroll
            for (int r = 0; r < 8; ++r)
                Eb[(size_t)(base + r) * HH + h] = ev[r];
        }
    }
}

// ---- Kernel 1b: KT_hi/lo[b][d][m] = f16 split of key[b][m][d] (transposed)
__global__ __launch_bounds__(256) void convert_kernel(
    const float* __restrict__ key, __half* __restrict__ KT_hi,
    __half* __restrict__ KT_lo) {
    __shared__ float t[64][65];
    const int tid = threadIdx.x;
    const int m0 = blockIdx.x * 64, d0 = blockIdx.y * 64, b = blockIdx.z;
    for (int i = tid; i < 1024; i += 256) {
        const int r = i >> 4, c4 = i & 15;
        const float4 v =
            *(const float4*)&key[((size_t)(b * MM + m0 + r)) * DD + d0 + c4 * 4];
        t[r][c4 * 4 + 0] = v.x; t[r][c4 * 4 + 1] = v.y;
        t[r][c4 * 4 + 2] = v.z; t[r][c4 * 4 + 3] = v.w;
    }
    __syncthreads();
    for (int i = tid; i < 4096; i += 256) {
        const int dr = i >> 6, mc = i & 63;
        const float f = t[mc][dr];
        const __half hi = __float2half(f);
        const __half lo = __float2half(f - __half2float(hi));
        const size_t o = ((size_t)(b * DD + d0 + dr)) * MM + m0 + mc;
        KT_hi[o] = hi;
        KT_lo[o] = lo;
    }
}

// ---- Kernel 2: Ph[b,n,m] = f16( exp(-2*sum_h v_h/(Ea*Eb+1) - 3) ) +
//      per-64m-chunk row sums psum[mq][b][n]. 4 h-terms share one rcp.
__global__ __launch_bounds__(256) void scores_kernel(
    const float* __restrict__ EaT, const float* __restrict__ Eb,
    const float* __restrict__ v_w, __half* __restrict__ Ph,
    float* __restrict__ psum) {
    __shared__ float b_s[64 * HH];  // 32KB, XOR-swizzled (slot ^ row&31)
    const int tid = threadIdx.x;
    const int mq = blockIdx.x;
    const int m0 = mq * 64, n0 = blockIdx.y * 32, b = blockIdx.z;

    for (int i = tid; i < 64 * 32; i += 256) {
        const int r = i >> 5, h4 = i & 31;
        *(float4*)&b_s[r * HH + ((h4 ^ (r & 31)) << 2)] =
            *(const float4*)&Eb[((size_t)(b * MM + m0 + r)) * HH + h4 * 4];
    }
    __syncthreads();

    const int ml = tid & 63;
    const int ng = __builtin_amdgcn_readfirstlane(threadIdx.x >> 6);
    const int mlx = ml & 31;
    const float* brow = &b_s[ml * HH];
    const float* aT = EaT + (size_t)b * HH * NN + (n0 + ng * 8);
    v2f acc[4] = {};
    for (int h4 = 0; h4 < 32; ++h4) {
        const float4 b4 = *(const float4*)&brow[(h4 ^ mlx) << 2];  // per-lane LDS
        const float4 w4 = *(const float4*)&v_w[h4 * 4];            // uniform
        const float* a0p = aT + (size_t)(h4 * 4 + 0) * NN;
        const float* a1p = aT + (size_t)(h4 * 4 + 1) * NN;
        const float* a2p = aT + (size_t)(h4 * 4 + 2) * NN;
        const float* a3p = aT + (size_t)(h4 * 4 + 3) * NN;
#pragma unroll
        for (int np = 0; np < 4; ++np) {
            const v2f a0 = *(const v2f*)&a0p[np * 2];  // uniform pairs
            const v2f a1 = *(const v2f*)&a1p[np * 2];
            const v2f a2 = *(const v2f*)&a2p[np * 2];
            const v2f a3 = *(const v2f*)&a3p[np * 2];
            const v2f u0 = a0 * b4.x + 1.0f;
            const v2f u1 = a1 * b4.y + 1.0f;
            const v2f u2 = a2 * b4.z + 1.0f;
            const v2f u3 = a3 * b4.w + 1.0f;
            const v2f p01 = u0 * u1, p23 = u2 * u3;
            const v2f An = w4.x * u1 + w4.y * u0;
            const v2f Bn = w4.z * u3 + w4.w * u2;
            const v2f num = An * p23 + Bn * p01;
            const v2f Pp = p01 * p23;
            v2f r2;
            r2.x = __builtin_amdgcn_rcpf(Pp.x);
            r2.y = __builtin_amdgcn_rcpf(Pp.y);
            acc[np] = num * r2 + acc[np];
        }
    }

    float pv[8];
#pragma unroll
    for (int np = 0; np < 4; ++np) {
        pv[np * 2 + 0] = __builtin_amdgcn_exp2f(fmaf(acc[np].x, NEG2LOG2E, SHIFT_C));
        pv[np * 2 + 1] = __builtin_amdgcn_exp2f(fmaf(acc[np].y, NEG2LOG2E, SHIFT_C));
    }
    const size_t prow = ((size_t)b * NN + n0 + ng * 8) * MM + m0 + ml;
#pragma unroll
    for (int j = 0; j < 8; ++j) {
        Ph[prow + (size_t)j * MM] = __float2half(pv[j]);
        float s = pv[j];
#pragma unroll
        for (int o = 32; o > 0; o >>= 1) s += __shfl_xor(s, o);
        if (ml == 0)
            psum[((size_t)mq * BB + b) * NN + n0 + ng * 8 + j] = s;
    }
}

// ---- Kernel 3: out[n,d] = (P @ K) / rowsum via MFMA 16x16x32 f16.
// Block 32n x 64d, 8 waves of 16n x 16d; K = hi + lo f16 split (fp32-grade).
__global__ __launch_bounds__(512) void attend_kernel(
    const __half* __restrict__ Ph, const __half* __restrict__ KT_hi,
    const __half* __restrict__ KT_lo, const float* __restrict__ psum,
    float* __restrict__ out) {
    __shared__ float inv[32];
    const int tid = threadIdx.x;
    const int n0 = blockIdx.x * 32, d0 = blockIdx.y * 64, b = blockIdx.z;

    if (tid < 32) {
        float s = 0.f;
#pragma unroll
        for (int q = 0; q < 16; ++q)
            s += psum[((size_t)q * BB + b) * NN + n0 + tid];
        inv[tid] = __builtin_amdgcn_rcpf(s);
    }

    const int wave = __builtin_amdgcn_readfirstlane(threadIdx.x >> 6);
    const int lane = tid & 63;
    const int nh = wave >> 2, dh = wave & 3;
    const int row16 = lane & 15, kg = lane >> 4;

    const h8* Ap = (const h8*)(Ph + ((size_t)(b * NN + n0 + nh * 16 + row16)) * MM + kg * 8);
    const h8* Bh = (const h8*)(KT_hi + ((size_t)(b * DD + d0 + dh * 16 + row16)) * MM + kg * 8);
    const h8* Bl = (const h8*)(KT_lo + ((size_t)(b * DD + d0 + dh * 16 + row16)) * MM + kg * 8);

    v4f ch = {0.f, 0.f, 0.f, 0.f}, cl = {0.f, 0.f, 0.f, 0.f};
    h8 a0 = Ap[0], bh0 = Bh[0], bl0 = Bl[0];
#pragma unroll 4
    for (int it = 0; it < 31; ++it) {
        const h8 a1 = Ap[(it + 1) * 4];
        const h8 bh1 = Bh[(it + 1) * 4];
        const h8 bl1 = Bl[(it + 1) * 4];
        ch = __builtin_amdgcn_mfma_f32_16x16x32_f16(a0, bh0, ch, 0, 0, 0);
        cl = __builtin_amdgcn_mfma_f32_16x16x32_f16(a0, bl0, cl, 0, 0, 0);
        a0 = a1; bh0 = bh1; bl0 = bl1;
    }
    ch = __builtin_amdgcn_mfma_f32_16x16x32_f16(a0, bh0, ch, 0, 0, 0);
    cl = __builtin_amdgcn_mfma_f32_16x16x32_f16(a0, bl0, cl, 0, 0, 0);

    __syncthreads();
    const int rbase = nh * 16 + kg * 4;
#pragma unroll
    for (int r = 0; r < 4; ++r) {
        const float v = (ch[r] + cl[r]) * inv[rbase + r];
        out[((size_t)(b * NN + n0 + rbase + r)) * DD + d0 + dh * 16 + row16] = v;
    }
}

extern "C" void kernel_launch(void* const* d_in, const int* in_sizes, int n_in,
                              void* d_out, int out_size, void* d_ws, size_t ws_size,
                              hipStream_t stream) {
    const float* query = (const float*)d_in[0];
    const float* key   = (const float*)d_in[1];
    const float* Wa_w  = (const float*)d_in[2];
    const float* Wa_b  = (const float*)d_in[3];
    const float* Wb_w  = (const float*)d_in[4];
    const float* Wb_b  = (const float*)d_in[5];
    const float* v_w   = (const float*)d_in[6];
    float* out = (float*)d_out;

    float* ws = (float*)d_ws;
    float* EaT  = ws;                          // BB*HH*NN f32
    float* Eb   = EaT + BB * NN * HH;          // BB*MM*HH f32
    float* psum = Eb + BB * MM * HH;           // 16*BB*NN f32
    __half* Ph    = (__half*)(psum + 16 * BB * NN);       // BB*NN*MM f16
    __half* KT_hi = Ph + (size_t)BB * NN * MM;            // BB*DD*MM f16
    __half* KT_lo = KT_hi + (size_t)BB * DD * MM;         // BB*DD*MM f16

    proj_kernel<<<dim3((BB * NN + BB * MM) / 8), dim3(256), 0, stream>>>(
        query, key, Wa_w, Wa_b, Wb_w, Wb_b, EaT, Eb);
    convert_kernel<<<dim3(MM / 64, DD / 64, BB), dim3(256), 0, stream>>>(
        key, KT_hi, KT_lo);
    scores_kernel<<<dim3(MM / 64, NN / 32, BB), dim3(256), 0, stream>>>(
        EaT, Eb, v_w, Ph, psum);
    attend_kernel<<<dim3(NN / 32, DD / 64, BB), dim3(512), 0, stream>>>(
        Ph, KT_hi, KT_lo, psum, out);
}